// Round 1
// 653.932 us; speedup vs baseline: 1.1644x; 1.1644x over previous
//
#include <hip/hip_runtime.h>
#include <stdint.h>

#define DIN 512
#define DOUT 512

typedef short bf16x8 __attribute__((ext_vector_type(8)));
typedef float floatx4 __attribute__((ext_vector_type(4)));
typedef float f32x4 __attribute__((ext_vector_type(4)));

static __device__ __forceinline__ ushort f2bf(float f) {
  uint32_t u = __float_as_uint(f);
  u += 0x7FFFu + ((u >> 16) & 1u);   // RTNE; values are finite/normal here
  return (ushort)(u >> 16);
}

// async global->LDS, 16B per lane; LDS dest is wave-uniform base + lane*16
static __device__ __forceinline__ void gload16(const ushort* g, ushort* l) {
  __builtin_amdgcn_global_load_lds(
      (const __attribute__((address_space(1))) unsigned int*)g,
      (__attribute__((address_space(3))) unsigned int*)l, 16, 0, 0);
}

// ---------------- fused: degcount | logmap0+bf16 | W->bf16 ----------------
__global__ __launch_bounds__(256) void fused1_kernel(
    const float* __restrict__ x, ushort* __restrict__ tanb,
    const float* __restrict__ W, ushort* __restrict__ Wbf,
    const int* __restrict__ dst, int* __restrict__ degi, int N, int E) {
  int bid = blockIdx.x;
  int degB = (E + 255) >> 8;
  if (bid < degB) {                      // degree count (atomic, latency-bound)
    int e = bid * 256 + threadIdx.x;
    if (e < E) atomicAdd(&degi[dst[e]], 1);
    return;
  }
  bid -= degB;
  int logB = (N + 3) >> 2;
  if (bid < logB) {                      // logmap0 + cast (memory-bound)
    int row = bid * 4 + (threadIdx.x >> 6);
    if (row >= N) return;
    int lane = threadIdx.x & 63;
    const f32x4* xr = (const f32x4*)(x + (size_t)row * DIN);
    f32x4 v0 = __builtin_nontemporal_load(xr + lane * 2);      // x read once
    f32x4 v1 = __builtin_nontemporal_load(xr + lane * 2 + 1);
    float ss = v0[0]*v0[0] + v0[1]*v0[1] + v0[2]*v0[2] + v0[3]*v0[3] +
               v1[0]*v1[0] + v1[1]*v1[1] + v1[2]*v1[2] + v1[3]*v1[3];
#pragma unroll
    for (int m = 32; m >= 1; m >>= 1) ss += __shfl_xor(ss, m, 64);
    float n = sqrtf(ss);
    float nc = fminf(fmaxf(n, 1e-7f), 1.0f - 1e-7f);
    float scale = atanhf(nc) / nc;
    union { ushort s[8]; uint4 v; } o;
    o.s[0] = f2bf(v0[0] * scale); o.s[1] = f2bf(v0[1] * scale);
    o.s[2] = f2bf(v0[2] * scale); o.s[3] = f2bf(v0[3] * scale);
    o.s[4] = f2bf(v1[0] * scale); o.s[5] = f2bf(v1[1] * scale);
    o.s[6] = f2bf(v1[2] * scale); o.s[7] = f2bf(v1[3] * scale);
    *(uint4*)(tanb + (size_t)row * DIN + lane * 8) = o.v;
    return;
  }
  bid -= logB;                           // W fp32 -> bf16 (256 blocks)
  int i = bid * 1024 + threadIdx.x * 4;
  float4 w4 = *(const float4*)(W + i);
  ushort4 o4;
  o4.x = f2bf(w4.x); o4.y = f2bf(w4.y); o4.z = f2bf(w4.z); o4.w = f2bf(w4.w);
  *(ushort4*)(Wbf + i) = o4;
}

// ---------------- CSR scans (unchanged) ----------------
__global__ __launch_bounds__(256) void scan1_kernel(const int* __restrict__ degi,
                                                    int* __restrict__ offs,
                                                    int* __restrict__ bsum, int N) {
  __shared__ int s[256];
  int tx = threadIdx.x;
  int i = blockIdx.x * 256 + tx;
  int v = (i < N) ? degi[i] : 0;
  s[tx] = v;
  __syncthreads();
#pragma unroll
  for (int d = 1; d < 256; d <<= 1) {
    int t = (tx >= d) ? s[tx - d] : 0;
    __syncthreads();
    s[tx] += t;
    __syncthreads();
  }
  if (i < N) offs[i] = s[tx] - v;
  if (tx == 255) bsum[blockIdx.x] = s[255];
}

__global__ __launch_bounds__(1024) void scan2_kernel(int* __restrict__ bsum, int B) {
  __shared__ int s[1024];
  int tx = threadIdx.x;
  int v = (tx < B) ? bsum[tx] : 0;
  s[tx] = v;
  __syncthreads();
#pragma unroll
  for (int d = 1; d < 1024; d <<= 1) {
    int t = (tx >= d) ? s[tx - d] : 0;
    __syncthreads();
    s[tx] += t;
    __syncthreads();
  }
  if (tx < B) bsum[tx] = s[tx] - v;
}

__global__ __launch_bounds__(256) void scan3_kernel(int* __restrict__ offs,
                                                    const int* __restrict__ bsum,
                                                    int* __restrict__ cursor, int N) {
  int i = blockIdx.x * 256 + threadIdx.x;
  if (i < N) {
    int o = offs[i] + bsum[blockIdx.x];
    offs[i] = o;
    cursor[i] = o;
  }
}

// ---------------- GEMM (m97 structure) + filladj merged ----------------
// Hb[m][n] = bf16( sum_k tan[m][k]*W[n][k] + b[n] )
// BM=128 BN=128 BK=64; 4 waves, 64x64 each; gload_lds16 staging with
// both-sides XOR swizzle; C staged through LDS for coalesced uint4 stores.
__global__ __launch_bounds__(256) void gemmfill_kernel(
    const ushort* __restrict__ A, const ushort* __restrict__ Bw,
    const float* __restrict__ bias, ushort* __restrict__ Hb, int M,
    const int* __restrict__ src, const int* __restrict__ dst,
    int* __restrict__ cursor, int* __restrict__ adj, int E, int FB) {
  __shared__ __align__(16) ushort smem[16384];  // As 16KB | Bs 16KB ; reused as Cs
  int bid = blockIdx.x;
  if (bid < FB) {                        // filladj blocks (run/overlap first)
    int e = bid * 256 + threadIdx.x;
    if (e < E) {
      int pos = atomicAdd(&cursor[dst[e]], 1);
      adj[pos] = src[e];
    }
    return;
  }
  bid -= FB;
  // XCD-grouping map (bijective, m204): raw id -> work id so the 4 blocks
  // sharing one A-tile all land on the same XCD's L2.
  int NB = (int)gridDim.x - FB;
  int q = NB >> 3, r = NB & 7;
  int xcd = bid & 7, off = bid >> 3;
  int w = (xcd < r) ? xcd * (q + 1) + off : r * (q + 1) + (xcd - r) * q + off;
  int n0 = (w & 3) * 128;
  int m0 = (w >> 2) * 128;

  ushort* As = smem;
  ushort* Bs = smem + 8192;
  int tid = threadIdx.x;
  int wave = tid >> 6, lane = tid & 63;
  int wm = (wave >> 1) * 64, wn = (wave & 1) * 64;
  int fr = lane & 15, fq = lane >> 4;
  int rsub = lane >> 3;                          // 0..7 (row within 8-row group)
  int ksw = ((lane & 7) ^ rsub) * 8;             // inverse-swizzled k element offset

  floatx4 acc[4][4] = {};

  for (int k0 = 0; k0 < DIN; k0 += 64) {
#pragma unroll
    for (int i = 0; i < 4; i++) {
      int g = wave * 4 + i;                      // 8-row group 0..15
      int ra = g * 8 + rsub;                     // tile row 0..127
      int gm = m0 + ra; if (gm >= M) gm = M - 1; // clamp tail rows
      gload16(A + (size_t)gm * DIN + k0 + ksw, As + g * 512);
      gload16(Bw + (size_t)(n0 + ra) * DIN + k0 + ksw, Bs + g * 512);
    }
    __syncthreads();                             // vmcnt(0) drain + barrier
#pragma unroll
    for (int kk = 0; kk < 2; kk++) {
      bf16x8 af[4], bg[4];
#pragma unroll
      for (int t = 0; t < 4; t++) {
        int ra = wm + t * 16 + fr;
        af[t] = *(const bf16x8*)(As + ra * 64 + (((kk * 4 + fq) ^ (ra & 7)) << 3));
        int rb = wn + t * 16 + fr;
        bg[t] = *(const bf16x8*)(Bs + rb * 64 + (((kk * 4 + fq) ^ (rb & 7)) << 3));
      }
#pragma unroll
      for (int mt = 0; mt < 4; mt++)
#pragma unroll
        for (int nt = 0; nt < 4; nt++)
          acc[mt][nt] = __builtin_amdgcn_mfma_f32_16x16x32_bf16(
              af[mt], bg[nt], acc[mt][nt], 0, 0, 0);
    }
    __syncthreads();
  }

  // epilogue: bias + bf16 -> swizzled LDS C-tile -> coalesced 16B stores
  int rq = fq * 4;
#pragma unroll
  for (int nt = 0; nt < 4; nt++) {
    int col = wn + nt * 16 + fr;
    float bb = bias[n0 + col];
    int c16 = col >> 3;
#pragma unroll
    for (int mt = 0; mt < 4; mt++) {
#pragma unroll
      for (int rr = 0; rr < 4; rr++) {
        int row = wm + mt * 16 + rq + rr;
        smem[row * 128 + (((c16 ^ (row & 7)) << 3) | (col & 7))] =
            f2bf(acc[mt][nt][rr] + bb);
      }
    }
  }
  __syncthreads();
#pragma unroll
  for (int p = 0; p < 8; p++) {
    int idx = p * 256 + tid;
    int row = idx >> 4, cc = idx & 15;
    uint4 v = *(const uint4*)(smem + row * 128 + ((cc ^ (row & 7)) << 3));
    int gm = m0 + row;
    if (gm < M) *(uint4*)(Hb + (size_t)gm * DOUT + n0 + cc * 8) = v;
  }
}

// ---------------- aggregate + mean + expmap0 (one wave per node) ----------------
static __device__ __forceinline__ void accum8(float* acc, uint4 v) {
  acc[0] += __uint_as_float(v.x << 16); acc[1] += __uint_as_float(v.x & 0xFFFF0000u);
  acc[2] += __uint_as_float(v.y << 16); acc[3] += __uint_as_float(v.y & 0xFFFF0000u);
  acc[4] += __uint_as_float(v.z << 16); acc[5] += __uint_as_float(v.z & 0xFFFF0000u);
  acc[6] += __uint_as_float(v.w << 16); acc[7] += __uint_as_float(v.w & 0xFFFF0000u);
}

__global__ __launch_bounds__(256) void aggregate_kernel(const ushort* __restrict__ hb,
                                                        const int* __restrict__ adj,
                                                        const int* __restrict__ offs,
                                                        const int* __restrict__ degi,
                                                        float* __restrict__ out, int N) {
  int row = blockIdx.x * 4 + (threadIdx.x >> 6);
  if (row >= N) return;
  int lane = threadIdx.x & 63;
  int dg = degi[row];
  int base = offs[row];
  float acc[8] = {0.f, 0.f, 0.f, 0.f, 0.f, 0.f, 0.f, 0.f};
  int j = 0;
  for (; j + 8 <= dg; j += 8) {           // 8 gathers in flight
    int av = adj[base + j + (lane & 7)];  // one load, broadcast via readlane
    uint4 v[8];
#pragma unroll
    for (int qq = 0; qq < 8; qq++) {
      int s = __builtin_amdgcn_readlane(av, qq);
      v[qq] = *(const uint4*)(hb + (size_t)s * DOUT + lane * 8);
    }
#pragma unroll
    for (int qq = 0; qq < 8; qq++) accum8(acc, v[qq]);
  }
  for (; j + 4 <= dg; j += 4) {
    int av = adj[base + j + (lane & 3)];
    uint4 v[4];
#pragma unroll
    for (int qq = 0; qq < 4; qq++) {
      int s = __builtin_amdgcn_readlane(av, qq);
      v[qq] = *(const uint4*)(hb + (size_t)s * DOUT + lane * 8);
    }
#pragma unroll
    for (int qq = 0; qq < 4; qq++) accum8(acc, v[qq]);
  }
  for (; j < dg; j++) {
    int s = __builtin_amdgcn_readfirstlane(adj[base + j]);
    uint4 a = *(const uint4*)(hb + (size_t)s * DOUT + lane * 8);
    accum8(acc, a);
  }
  float inv = 1.0f / fmaxf((float)dg, 1.0f);
  float ss = 0.f;
#pragma unroll
  for (int k = 0; k < 8; k++) ss += acc[k] * acc[k];
#pragma unroll
  for (int m = 32; m >= 1; m >>= 1) ss += __shfl_xor(ss, m, 64);
  float n = fmaxf(inv * sqrtf(ss), 1e-7f);   // ||mean||, clamped like reference
  float sc = tanhf(n) / n * inv;
  f32x4 o0 = {acc[0] * sc, acc[1] * sc, acc[2] * sc, acc[3] * sc};
  f32x4 o1 = {acc[4] * sc, acc[5] * sc, acc[6] * sc, acc[7] * sc};
  float* orow = out + (size_t)row * DOUT + lane * 8;
  // nontemporal: out is write-once; keep L2/L3 for the hb gather working set
  __builtin_nontemporal_store(o0, (f32x4*)orow);
  __builtin_nontemporal_store(o1, (f32x4*)(orow + 4));
}

extern "C" void kernel_launch(void* const* d_in, const int* in_sizes, int n_in,
                              void* d_out, int out_size, void* d_ws, size_t ws_size,
                              hipStream_t stream) {
  const float* x = (const float*)d_in[0];
  const int* src = (const int*)d_in[1];
  const int* dst = (const int*)d_in[2];
  const float* W = (const float*)d_in[3];
  const float* b = (const float*)d_in[4];
  int N = in_sizes[0] / DIN;
  int E = in_sizes[1];
  float* out = (float*)d_out;

  // workspace layout (unchanged)
  char* ws = (char*)d_ws;
  size_t off = 0;
  ushort* Wbf = (ushort*)(ws + off); off += (size_t)DOUT * DIN * 2;
  ushort* tanb = (ushort*)(ws + off); off += (size_t)N * DIN * 2;
  ushort* hb = (ushort*)(ws + off); off += (size_t)N * DIN * 2;
  off = (off + 255) & ~(size_t)255;
  int* degi = (int*)(ws + off); off += (size_t)N * 4;
  off = (off + 255) & ~(size_t)255;
  int* offs = (int*)(ws + off); off += (size_t)N * 4;
  off = (off + 255) & ~(size_t)255;
  int* cursor = (int*)(ws + off); off += (size_t)N * 4;
  off = (off + 255) & ~(size_t)255;
  int* bsum = (int*)(ws + off); off += 1024 * 4;
  int* adj = (int*)(ws + off); off += (size_t)E * 4;

  hipMemsetAsync(degi, 0, (size_t)N * 4, stream);

  int degB = (E + 255) >> 8;             // 3907
  int logB = (N + 3) >> 2;               // 25000
  int wB = (DOUT * DIN) / 1024;          // 256
  fused1_kernel<<<degB + logB + wB, 256, 0, stream>>>(x, tanb, W, Wbf, dst, degi, N, E);

  int B1 = (N + 255) / 256;              // <= 1024 blocks for N <= 262144
  scan1_kernel<<<B1, 256, 0, stream>>>(degi, offs, bsum, N);
  scan2_kernel<<<1, 1024, 0, stream>>>(bsum, B1);
  scan3_kernel<<<B1, 256, 0, stream>>>(offs, bsum, cursor, N);

  int MB = (N + 127) >> 7;               // 782 m-tiles
  int FB = degB;                         // filladj blocks lead the gemm grid
  gemmfill_kernel<<<FB + 4 * MB, 256, 0, stream>>>(tanb, Wbf, b, hb, N,
                                                   src, dst, cursor, adj, E, FB);

  aggregate_kernel<<<(N + 3) / 4, 256, 0, stream>>>(hb, adj, offs, degi, out, N);
}